// Round 3
// baseline (945.096 us; speedup 1.0000x reference)
//
#include <hip/hip_runtime.h>

#define N_NODES 100000
#define N_EDGES 3200000
#define N_GRAPHS 2048
#define DIM 32
#define FEAT 78
#define OUT_DIM 128
#define BN_EPS 1e-5f

#define BSHIFT 9
#define BSIZE 512                      // nodes per bucket
#define NB ((N_NODES + BSIZE - 1) / BSIZE)   // 196 buckets
#define CHUNK 8192                     // edges per scatter block

// ---------------- K1: coarse bucket histogram ----------------
__global__ __launch_bounds__(256) void bucket_hist_kernel(const int* __restrict__ dst,
                                                          int* __restrict__ bcnt) {
    __shared__ int lh[256];
    int tid = threadIdx.x;
    lh[tid] = 0;
    __syncthreads();
    int i = blockIdx.x * blockDim.x + tid;
    int stride = gridDim.x * blockDim.x;
    for (; i < N_EDGES; i += stride)
        atomicAdd(&lh[dst[i] >> BSHIFT], 1);
    __syncthreads();
    if (tid < NB && lh[tid])
        atomicAdd(&bcnt[tid], lh[tid]);
}

// ---------------- K2: scan over buckets ----------------
__global__ __launch_bounds__(256) void bucket_scan_kernel(const int* __restrict__ bcnt,
                                                          int* __restrict__ bstart,
                                                          int* __restrict__ bcursor,
                                                          int* __restrict__ rowst) {
    __shared__ int sc[256];
    int tid = threadIdx.x;
    int v = (tid < NB) ? bcnt[tid] : 0;
    sc[tid] = v;
    __syncthreads();
    for (int off = 1; off < 256; off <<= 1) {
        int nv = (tid >= off) ? sc[tid - off] : 0;
        __syncthreads();
        sc[tid] += nv;
        __syncthreads();
    }
    if (tid < NB) {
        int ex = sc[tid] - v;
        bstart[tid] = ex;
        bcursor[tid] = ex;
    }
    if (tid == 0) {
        bstart[NB] = N_EDGES;
        rowst[N_NODES] = N_EDGES;
    }
}

// ---------------- K3: multisplit scatter into bucket segments ----------------
__global__ __launch_bounds__(256) void bucket_scatter_kernel(const int* __restrict__ src,
                                                             const int* __restrict__ dst,
                                                             int* __restrict__ bcursor,
                                                             int* __restrict__ bsrc,
                                                             unsigned short* __restrict__ blow) {
    __shared__ int lsrc[CHUNK];
    __shared__ int ldst[CHUNK];
    __shared__ int lhist[256];
    __shared__ int sc[256];
    __shared__ int lpre[256];
    __shared__ int gbase[256];
    __shared__ int lcur[256];
    int tid = threadIdx.x;
    int base = blockIdx.x * CHUNK;
    int n = N_EDGES - base; if (n > CHUNK) n = CHUNK;

    lhist[tid] = 0;
    __syncthreads();
    for (int i = tid; i < n; i += 256)
        atomicAdd(&lhist[dst[base + i] >> BSHIFT], 1);
    __syncthreads();
    int v = lhist[tid];
    sc[tid] = v;
    __syncthreads();
    for (int off = 1; off < 256; off <<= 1) {
        int nv = (tid >= off) ? sc[tid - off] : 0;
        __syncthreads();
        sc[tid] += nv;
        __syncthreads();
    }
    int ex = sc[tid] - v;
    lpre[tid] = ex;
    lcur[tid] = ex;
    if (tid < NB && v)
        gbase[tid] = atomicAdd(&bcursor[tid], v);
    __syncthreads();
    // local scatter (bucket-ordered) into LDS
    for (int i = tid; i < n; i += 256) {
        int d = dst[base + i];
        int s = src[base + i];
        int b = d >> BSHIFT;
        int pos = atomicAdd(&lcur[b], 1);
        lsrc[pos] = s;
        ldst[pos] = d;
    }
    __syncthreads();
    // coalesced flush
    for (int i = tid; i < n; i += 256) {
        int d = ldst[i];
        int b = d >> BSHIFT;
        int gpos = gbase[b] + (i - lpre[b]);
        bsrc[gpos] = lsrc[i];
        blow[gpos] = (unsigned short)(d & (BSIZE - 1));
    }
}

// ---------------- K4: per-bucket counting sort -> csr + rowst ----------------
__global__ __launch_bounds__(256) void node_sort_kernel(const int* __restrict__ bstart,
                                                        const int* __restrict__ bsrc,
                                                        const unsigned short* __restrict__ blow,
                                                        int* __restrict__ csr,
                                                        int* __restrict__ rowst) {
    __shared__ int lcnt[BSIZE];
    __shared__ int sc[256];
    __shared__ int lpre[BSIZE];
    __shared__ int lcur[BSIZE];
    int tid = threadIdx.x;
    int b = blockIdx.x;
    int ss = bstart[b], se = bstart[b + 1];
    lcnt[tid] = 0; lcnt[tid + 256] = 0;
    __syncthreads();
    for (int i = ss + tid; i < se; i += 256)
        atomicAdd(&lcnt[blow[i]], 1);
    __syncthreads();
    int a0 = lcnt[2 * tid], a1 = lcnt[2 * tid + 1];
    int s = a0 + a1;
    sc[tid] = s;
    __syncthreads();
    for (int off = 1; off < 256; off <<= 1) {
        int nv = (tid >= off) ? sc[tid - off] : 0;
        __syncthreads();
        sc[tid] += nv;
        __syncthreads();
    }
    int ex = sc[tid] - s;
    lpre[2 * tid] = ex;
    lpre[2 * tid + 1] = ex + a0;
    lcur[2 * tid] = ex;
    lcur[2 * tid + 1] = ex + a0;
    __syncthreads();
    int node_base = b << BSHIFT;
    for (int j = tid; j < BSIZE; j += 256) {
        int node = node_base + j;
        if (node < N_NODES) rowst[node] = ss + lpre[j];
    }
    for (int i = ss + tid; i < se; i += 256) {
        int nloc = blow[i];
        int pos = atomicAdd(&lcur[nloc], 1);
        csr[ss + pos] = bsrc[i];
    }
}

// ---------------- t = x @ W1a  (78 -> 32) ----------------
__global__ __launch_bounds__(256) void transform1_kernel(const float* __restrict__ x,
                                                         const float* __restrict__ W,
                                                         float* __restrict__ t) {
    __shared__ float Wl[FEAT * DIM];
    for (int i = threadIdx.x; i < FEAT * DIM; i += blockDim.x) Wl[i] = W[i];
    __syncthreads();
    int lane = threadIdx.x & 31;
    int group = threadIdx.x >> 5;
    int gpb = blockDim.x >> 5;
    for (int node = blockIdx.x * gpb + group; node < N_NODES; node += gridDim.x * gpb) {
        const float* xr = x + (size_t)node * FEAT;
        float r0 = xr[lane];
        float r1 = xr[32 + lane];
        float r2 = (lane < FEAT - 64) ? xr[64 + lane] : 0.f;
        float acc = 0.f;
        #pragma unroll
        for (int k = 0; k < 32; ++k)
            acc += __shfl(r0, k, 32) * Wl[k * DIM + lane];
        #pragma unroll
        for (int k = 0; k < 32; ++k)
            acc += __shfl(r1, k, 32) * Wl[(32 + k) * DIM + lane];
        #pragma unroll
        for (int k = 0; k < FEAT - 64; ++k)
            acc += __shfl(r2, k, 32) * Wl[(64 + k) * DIM + lane];
        t[node * DIM + lane] = acc;
    }
}

// ---------------- agg (wide float4 gather) + bias + relu + @Wb + bias + relu + BN stats ----------------
// One 64-lane wave per node: lane = (slot r = l>>3) x (float4 col q = l&7).
// Each iteration gathers 16 neighbor rows (2 float4 loads/lane in flight).
__global__ __launch_bounds__(256) void agg_mlp_kernel(const float* __restrict__ t,
                                                      const int* __restrict__ row_start,
                                                      const int* __restrict__ csr,
                                                      const float* __restrict__ bias_a,
                                                      const float* __restrict__ Wb,
                                                      const float* __restrict__ bias_b,
                                                      float* __restrict__ h_out,
                                                      float* __restrict__ stats) {
    __shared__ float Wl[DIM * DIM];
    __shared__ float lsum[DIM], lsumsq[DIM];
    for (int i = threadIdx.x; i < DIM * DIM; i += blockDim.x) Wl[i] = Wb[i];
    if (threadIdx.x < DIM) { lsum[threadIdx.x] = 0.f; lsumsq[threadIdx.x] = 0.f; }
    __syncthreads();
    int l = threadIdx.x & 63;
    int wave = threadIdx.x >> 6;          // 0..3
    int q = l & 7;                        // which float4 of the row
    int r = l >> 3;                       // neighbor slot 0..7
    int lane32 = l & 31;
    float ba = bias_a[lane32], bbv = bias_b[lane32];
    float ls = 0.f, lss = 0.f;
    const int wpb = 4;                    // waves per block
    for (int node = blockIdx.x * wpb + wave; node < N_NODES; node += gridDim.x * wpb) {
        int rs = row_start[node], re = row_start[node + 1];
        float4 a4 = {0.f, 0.f, 0.f, 0.f};
        for (int p = rs; p < re; p += 16) {
            int i0 = p + r;
            int i1 = i0 + 8;
            float4 v0 = {0.f, 0.f, 0.f, 0.f};
            float4 v1 = {0.f, 0.f, 0.f, 0.f};
            if (i0 < re) v0 = *(const float4*)(t + (size_t)csr[i0] * DIM + (q << 2));
            if (i1 < re) v1 = *(const float4*)(t + (size_t)csr[i1] * DIM + (q << 2));
            a4.x += v0.x + v1.x;
            a4.y += v0.y + v1.y;
            a4.z += v0.z + v1.z;
            a4.w += v0.w + v1.w;
        }
        // reduce over the 8 slots (lane bits 3,4,5)
        #pragma unroll
        for (int m = 8; m <= 32; m <<= 1) {
            a4.x += __shfl_xor(a4.x, m);
            a4.y += __shfl_xor(a4.y, m);
            a4.z += __shfl_xor(a4.z, m);
            a4.w += __shfl_xor(a4.w, m);
        }
        // redistribute to lane=dim layout: dim d lives in component (d&3) of lane (d>>2)
        float t0 = __shfl(a4.x, lane32 >> 2);
        float t1 = __shfl(a4.y, lane32 >> 2);
        float t2 = __shfl(a4.z, lane32 >> 2);
        float t3 = __shfl(a4.w, lane32 >> 2);
        int sel = lane32 & 3;
        float agg = (sel == 0) ? t0 : (sel == 1) ? t1 : (sel == 2) ? t2 : t3;
        agg += t[(size_t)node * DIM + lane32];   // self term
        float acc = fmaxf(agg + ba, 0.f);
        float y = bbv;
        #pragma unroll
        for (int k = 0; k < DIM; ++k)
            y += __shfl(acc, k, 32) * Wl[k * DIM + lane32];
        y = fmaxf(y, 0.f);
        if (l < 32) {
            h_out[(size_t)node * DIM + lane32] = y;
            ls += y;
            lss += y * y;
        }
    }
    if (l < 32) {
        atomicAdd(&lsum[lane32], ls);
        atomicAdd(&lsumsq[lane32], lss);
    }
    __syncthreads();
    if (threadIdx.x < DIM) {
        atomicAdd(&stats[threadIdx.x], lsum[threadIdx.x]);
        atomicAdd(&stats[DIM + threadIdx.x], lsumsq[threadIdx.x]);
    }
}

// ---------------- BN normalize + t = hnorm @ Wa (for next layer) ----------------
__global__ __launch_bounds__(256) void bn_transform_kernel(const float* __restrict__ h,
                                                           const float* __restrict__ stats,
                                                           const float* __restrict__ gamma,
                                                           const float* __restrict__ beta,
                                                           const float* __restrict__ Wa,
                                                           float* __restrict__ t) {
    __shared__ float Wl[DIM * DIM];
    for (int i = threadIdx.x; i < DIM * DIM; i += blockDim.x) Wl[i] = Wa[i];
    __syncthreads();
    int lane = threadIdx.x & 31;
    int group = threadIdx.x >> 5;
    int gpb = blockDim.x >> 5;
    float mu = stats[lane] * (1.f / N_NODES);
    float var = stats[DIM + lane] * (1.f / N_NODES) - mu * mu;
    float inv = rsqrtf(var + BN_EPS);
    float a = gamma[lane] * inv;
    float c = beta[lane] - mu * a;
    for (int node = blockIdx.x * gpb + group; node < N_NODES; node += gridDim.x * gpb) {
        float v = h[node * DIM + lane] * a + c;
        float y = 0.f;
        #pragma unroll
        for (int k = 0; k < DIM; ++k)
            y += __shfl(v, k, 32) * Wl[k * DIM + lane];
        t[node * DIM + lane] = y;
    }
}

// ---------------- final BN + global_add_pool (run-length compressed, batch sorted) ----------------
#define POOL_BLOCKS 512
__global__ __launch_bounds__(256) void bn_pool_kernel(const float* __restrict__ h,
                                                      const float* __restrict__ stats,
                                                      const float* __restrict__ gamma,
                                                      const float* __restrict__ beta,
                                                      const int* __restrict__ batch,
                                                      float* __restrict__ pooled) {
    int lane = threadIdx.x & 31;
    int group = threadIdx.x >> 5;
    float mu = stats[lane] * (1.f / N_NODES);
    float var = stats[DIM + lane] * (1.f / N_NODES) - mu * mu;
    float inv = rsqrtf(var + BN_EPS);
    float a = gamma[lane] * inv;
    float c = beta[lane] - mu * a;
    const int ngroups = POOL_BLOCKS * 8;
    const int chunk = (N_NODES + ngroups - 1) / ngroups;
    int g = blockIdx.x * 8 + group;
    int start = g * chunk;
    if (start >= N_NODES) return;
    int end = start + chunk; if (end > N_NODES) end = N_NODES;
    int cur = batch[start];
    float s = 0.f;
    for (int node = start; node < end; ++node) {
        float v = h[node * DIM + lane] * a + c;
        int bg = batch[node];
        if (bg != cur) {
            atomicAdd(&pooled[cur * DIM + lane], s);
            s = 0.f;
            cur = bg;
        }
        s += v;
    }
    atomicAdd(&pooled[cur * DIM + lane], s);
}

// ---------------- out = relu(pooled @ Wfc + bfc) ----------------
__global__ __launch_bounds__(256) void fc_kernel(const float* __restrict__ pooled,
                                                 const float* __restrict__ Wfc,
                                                 const float* __restrict__ bfc,
                                                 float* __restrict__ out) {
    __shared__ float Wl[DIM * OUT_DIM];
    for (int i = threadIdx.x; i < DIM * OUT_DIM; i += blockDim.x) Wl[i] = Wfc[i];
    __syncthreads();
    int idx = blockIdx.x * blockDim.x + threadIdx.x;
    int stride = gridDim.x * blockDim.x;
    for (; idx < N_GRAPHS * OUT_DIM; idx += stride) {
        int g = idx >> 7;
        int o = idx & 127;
        float acc = bfc[o];
        #pragma unroll
        for (int k = 0; k < DIM; ++k)
            acc += pooled[g * DIM + k] * Wl[k * OUT_DIM + o];
        out[idx] = fmaxf(acc, 0.f);
    }
}

extern "C" void kernel_launch(void* const* d_in, const int* in_sizes, int n_in,
                              void* d_out, int out_size, void* d_ws, size_t ws_size,
                              hipStream_t stream) {
    const float* x   = (const float*)d_in[0];
    const int* eidx  = (const int*)d_in[1];
    const int* src   = eidx;
    const int* dst   = eidx + N_EDGES;
    const int* batch = (const int*)d_in[2];
    const float* W1a = (const float*)d_in[3];
    const float* b1a = (const float*)d_in[4];
    const float* W1b = (const float*)d_in[5];
    const float* b1b = (const float*)d_in[6];
    const float* Wa  = (const float*)d_in[7];
    const float* ba  = (const float*)d_in[8];
    const float* Wb  = (const float*)d_in[9];
    const float* bb  = (const float*)d_in[10];
    const float* gamma = (const float*)d_in[11];
    const float* beta  = (const float*)d_in[12];
    const float* Wfc = (const float*)d_in[13];
    const float* bfc = (const float*)d_in[14];
    float* out = (float*)d_out;

    float* wsf    = (float*)d_ws;
    float* t      = wsf;                                 // 3.2M floats
    float* hbuf   = t + (size_t)N_NODES * DIM;           // 3.2M floats
    float* stats  = hbuf + (size_t)N_NODES * DIM;        // 5 * 64
    float* pooled = stats + 5 * 64;                      // 65536
    int* csr      = (int*)(pooled + N_GRAPHS * DIM);     // 3.2M
    int* rowst    = csr + N_EDGES;                       // N_NODES+1
    int* bcnt     = rowst + N_NODES + 1;                 // 256
    int* bstart   = bcnt + 256;                          // NB+1
    int* bcursor  = bstart + NB + 1;                     // 256

    // bucket pair arrays alias t/h (dead until transform1)
    int* bsrc           = (int*)t;
    unsigned short* blow = (unsigned short*)hbuf;

    hipMemsetAsync(bcnt, 0, 256 * sizeof(int), stream);
    hipMemsetAsync(stats, 0, 5 * 64 * sizeof(float), stream);
    hipMemsetAsync(pooled, 0, N_GRAPHS * DIM * sizeof(float), stream);

    bucket_hist_kernel<<<1024, 256, 0, stream>>>(dst, bcnt);
    bucket_scan_kernel<<<1, 256, 0, stream>>>(bcnt, bstart, bcursor, rowst);
    bucket_scatter_kernel<<<(N_EDGES + CHUNK - 1) / CHUNK, 256, 0, stream>>>(src, dst, bcursor, bsrc, blow);
    node_sort_kernel<<<NB, 256, 0, stream>>>(bstart, bsrc, blow, csr, rowst);

    transform1_kernel<<<2048, 256, 0, stream>>>(x, W1a, t);
    agg_mlp_kernel<<<2048, 256, 0, stream>>>(t, rowst, csr, b1a, W1b, b1b, hbuf, stats + 0);
    for (int i = 0; i < 4; ++i) {
        bn_transform_kernel<<<2048, 256, 0, stream>>>(hbuf, stats + i * 64,
                                                      gamma + i * DIM, beta + i * DIM,
                                                      Wa + i * DIM * DIM, t);
        agg_mlp_kernel<<<2048, 256, 0, stream>>>(t, rowst, csr, ba + i * DIM,
                                                 Wb + i * DIM * DIM, bb + i * DIM,
                                                 hbuf, stats + (i + 1) * 64);
    }
    bn_pool_kernel<<<POOL_BLOCKS, 256, 0, stream>>>(hbuf, stats + 4 * 64,
                                                    gamma + 4 * DIM, beta + 4 * DIM, batch, pooled);
    fc_kernel<<<1024, 256, 0, stream>>>(pooled, Wfc, bfc, out);
}

// Round 4
// 917.104 us; speedup vs baseline: 1.0305x; 1.0305x over previous
//
#include <hip/hip_runtime.h>
#include <hip/hip_fp16.h>

#define N_NODES 100000
#define N_EDGES 3200000
#define N_GRAPHS 2048
#define DIM 32
#define FEAT 78
#define OUT_DIM 128
#define BN_EPS 1e-5f

#define BSHIFT 9
#define BSIZE 512                      // nodes per bucket
#define NB ((N_NODES + BSIZE - 1) / BSIZE)   // 196 buckets
#define CHUNK 8192                     // edges per scatter block

// ---------------- K1: coarse bucket histogram ----------------
__global__ __launch_bounds__(256) void bucket_hist_kernel(const int* __restrict__ dst,
                                                          int* __restrict__ bcnt) {
    __shared__ int lh[256];
    int tid = threadIdx.x;
    lh[tid] = 0;
    __syncthreads();
    int i = blockIdx.x * blockDim.x + tid;
    int stride = gridDim.x * blockDim.x;
    for (; i < N_EDGES; i += stride)
        atomicAdd(&lh[dst[i] >> BSHIFT], 1);
    __syncthreads();
    if (tid < NB && lh[tid])
        atomicAdd(&bcnt[tid], lh[tid]);
}

// ---------------- K2: scan over buckets ----------------
__global__ __launch_bounds__(256) void bucket_scan_kernel(const int* __restrict__ bcnt,
                                                          int* __restrict__ bstart,
                                                          int* __restrict__ bcursor,
                                                          int* __restrict__ rowst) {
    __shared__ int sc[256];
    int tid = threadIdx.x;
    int v = (tid < NB) ? bcnt[tid] : 0;
    sc[tid] = v;
    __syncthreads();
    for (int off = 1; off < 256; off <<= 1) {
        int nv = (tid >= off) ? sc[tid - off] : 0;
        __syncthreads();
        sc[tid] += nv;
        __syncthreads();
    }
    if (tid < NB) {
        int ex = sc[tid] - v;
        bstart[tid] = ex;
        bcursor[tid] = ex;
    }
    if (tid == 0) {
        bstart[NB] = N_EDGES;
        rowst[N_NODES] = N_EDGES;
    }
}

// ---------------- K3: multisplit scatter into bucket segments ----------------
__global__ __launch_bounds__(256) void bucket_scatter_kernel(const int* __restrict__ src,
                                                             const int* __restrict__ dst,
                                                             int* __restrict__ bcursor,
                                                             int* __restrict__ bsrc,
                                                             unsigned short* __restrict__ blow) {
    __shared__ int lsrc[CHUNK];
    __shared__ int ldst[CHUNK];
    __shared__ int lhist[256];
    __shared__ int sc[256];
    __shared__ int lpre[256];
    __shared__ int gbase[256];
    __shared__ int lcur[256];
    int tid = threadIdx.x;
    int base = blockIdx.x * CHUNK;
    int n = N_EDGES - base; if (n > CHUNK) n = CHUNK;

    lhist[tid] = 0;
    __syncthreads();
    for (int i = tid; i < n; i += 256)
        atomicAdd(&lhist[dst[base + i] >> BSHIFT], 1);
    __syncthreads();
    int v = lhist[tid];
    sc[tid] = v;
    __syncthreads();
    for (int off = 1; off < 256; off <<= 1) {
        int nv = (tid >= off) ? sc[tid - off] : 0;
        __syncthreads();
        sc[tid] += nv;
        __syncthreads();
    }
    int ex = sc[tid] - v;
    lpre[tid] = ex;
    lcur[tid] = ex;
    if (tid < NB && v)
        gbase[tid] = atomicAdd(&bcursor[tid], v);
    __syncthreads();
    for (int i = tid; i < n; i += 256) {
        int d = dst[base + i];
        int s = src[base + i];
        int b = d >> BSHIFT;
        int pos = atomicAdd(&lcur[b], 1);
        lsrc[pos] = s;
        ldst[pos] = d;
    }
    __syncthreads();
    for (int i = tid; i < n; i += 256) {
        int d = ldst[i];
        int b = d >> BSHIFT;
        int gpos = gbase[b] + (i - lpre[b]);
        bsrc[gpos] = lsrc[i];
        blow[gpos] = (unsigned short)(d & (BSIZE - 1));
    }
}

// ---------------- K4: per-bucket counting sort -> csr + rowst ----------------
__global__ __launch_bounds__(256) void node_sort_kernel(const int* __restrict__ bstart,
                                                        const int* __restrict__ bsrc,
                                                        const unsigned short* __restrict__ blow,
                                                        int* __restrict__ csr,
                                                        int* __restrict__ rowst) {
    __shared__ int lcnt[BSIZE];
    __shared__ int sc[256];
    __shared__ int lpre[BSIZE];
    __shared__ int lcur[BSIZE];
    int tid = threadIdx.x;
    int b = blockIdx.x;
    int ss = bstart[b], se = bstart[b + 1];
    lcnt[tid] = 0; lcnt[tid + 256] = 0;
    __syncthreads();
    for (int i = ss + tid; i < se; i += 256)
        atomicAdd(&lcnt[blow[i]], 1);
    __syncthreads();
    int a0 = lcnt[2 * tid], a1 = lcnt[2 * tid + 1];
    int s = a0 + a1;
    sc[tid] = s;
    __syncthreads();
    for (int off = 1; off < 256; off <<= 1) {
        int nv = (tid >= off) ? sc[tid - off] : 0;
        __syncthreads();
        sc[tid] += nv;
        __syncthreads();
    }
    int ex = sc[tid] - s;
    lpre[2 * tid] = ex;
    lpre[2 * tid + 1] = ex + a0;
    lcur[2 * tid] = ex;
    lcur[2 * tid + 1] = ex + a0;
    __syncthreads();
    int node_base = b << BSHIFT;
    for (int j = tid; j < BSIZE; j += 256) {
        int node = node_base + j;
        if (node < N_NODES) rowst[node] = ss + lpre[j];
    }
    for (int i = ss + tid; i < se; i += 256) {
        int nloc = blow[i];
        int pos = atomicAdd(&lcur[nloc], 1);
        csr[ss + pos] = bsrc[i];
    }
}

// ---------------- t16 = fp16(x @ W1a)  (78 -> 32) ----------------
__global__ __launch_bounds__(256) void transform1_kernel(const float* __restrict__ x,
                                                         const float* __restrict__ W,
                                                         __half* __restrict__ t) {
    __shared__ float Wl[FEAT * DIM];
    for (int i = threadIdx.x; i < FEAT * DIM; i += blockDim.x) Wl[i] = W[i];
    __syncthreads();
    int lane = threadIdx.x & 31;
    int group = threadIdx.x >> 5;
    int gpb = blockDim.x >> 5;
    for (int node = blockIdx.x * gpb + group; node < N_NODES; node += gridDim.x * gpb) {
        const float* xr = x + (size_t)node * FEAT;
        float r0 = xr[lane];
        float r1 = xr[32 + lane];
        float r2 = (lane < FEAT - 64) ? xr[64 + lane] : 0.f;
        float acc = 0.f;
        #pragma unroll
        for (int k = 0; k < 32; ++k)
            acc += __shfl(r0, k, 32) * Wl[k * DIM + lane];
        #pragma unroll
        for (int k = 0; k < 32; ++k)
            acc += __shfl(r1, k, 32) * Wl[(32 + k) * DIM + lane];
        #pragma unroll
        for (int k = 0; k < FEAT - 64; ++k)
            acc += __shfl(r2, k, 32) * Wl[(64 + k) * DIM + lane];
        t[((size_t)node << 5) + lane] = __float2half(acc);
    }
}

// ---------------- prep: fold BN into next layer's Wa ----------------
// Wp[0..1023] = diag(a) * Wa ; Wp[1024..1055] = (beta - mu*a) @ Wa
__global__ __launch_bounds__(1024) void prep_kernel(const float* __restrict__ stats,
                                                    const float* __restrict__ gamma,
                                                    const float* __restrict__ beta,
                                                    const float* __restrict__ Wa,
                                                    float* __restrict__ Wp) {
    __shared__ float a[DIM], c[DIM];
    int tid = threadIdx.x;
    if (tid < DIM) {
        float mu = stats[tid] * (1.f / N_NODES);
        float var = stats[DIM + tid] * (1.f / N_NODES) - mu * mu;
        float av = gamma[tid] * rsqrtf(var + BN_EPS);
        a[tid] = av;
        c[tid] = beta[tid] - mu * av;
    }
    __syncthreads();
    int k = tid >> 5;
    Wp[tid] = a[k] * Wa[tid];
    if (tid < DIM) {
        float s = 0.f;
        for (int kk = 0; kk < DIM; ++kk)
            s += c[kk] * Wa[kk * DIM + tid];
        Wp[DIM * DIM + tid] = s;
    }
}

__global__ __launch_bounds__(1024) void prep_id_kernel(float* __restrict__ Wp) {
    int tid = threadIdx.x;
    Wp[tid] = ((tid >> 5) == (tid & 31)) ? 1.f : 0.f;
    if (tid < DIM) Wp[DIM * DIM + tid] = 0.f;
}

// ---------------- agg (fp16 gather, 1 line/row) + W' + ba + relu + Wb + bb + relu + stats ----
// One 64-lane wave per node: q = l&3 (16B chunk of 64B row), r = l>>2 (16 row slots).
__global__ __launch_bounds__(256) void agg_kernel(const __half* __restrict__ hin,
                                                  const int* __restrict__ row_start,
                                                  const int* __restrict__ csr,
                                                  const float* __restrict__ Wp,
                                                  const float* __restrict__ bias_a,
                                                  const float* __restrict__ Wb,
                                                  const float* __restrict__ bias_b,
                                                  __half* __restrict__ hout,
                                                  float* __restrict__ stats) {
    __shared__ float Wpl[DIM * DIM];
    __shared__ float Wbl[DIM * DIM];
    __shared__ float cwl[DIM];
    __shared__ float lsum[DIM], lsumsq[DIM];
    for (int i = threadIdx.x; i < DIM * DIM; i += 256) { Wpl[i] = Wp[i]; Wbl[i] = Wb[i]; }
    if (threadIdx.x < DIM) {
        cwl[threadIdx.x] = Wp[DIM * DIM + threadIdx.x];
        lsum[threadIdx.x] = 0.f; lsumsq[threadIdx.x] = 0.f;
    }
    __syncthreads();
    int l = threadIdx.x & 63;
    int wave = threadIdx.x >> 6;
    int q = l & 3;
    int r = l >> 2;
    int l32 = l & 31;
    float ba = bias_a[l32], bbv = bias_b[l32];
    float ls = 0.f, lss = 0.f;
    for (int node = blockIdx.x * 4 + wave; node < N_NODES; node += gridDim.x * 4) {
        int rs = row_start[node], re = row_start[node + 1];
        float a0 = 0.f, a1 = 0.f, a2 = 0.f, a3 = 0.f, a4 = 0.f, a5 = 0.f, a6 = 0.f, a7 = 0.f;
        for (int p = rs; p < re; p += 32) {
            int i0 = p + r;
            int i1 = i0 + 16;
            uint4 v0 = {0, 0, 0, 0}, v1 = {0, 0, 0, 0};
            if (i0 < re) v0 = *(const uint4*)(hin + (((size_t)csr[i0]) << 5) + (q << 3));
            if (i1 < re) v1 = *(const uint4*)(hin + (((size_t)csr[i1]) << 5) + (q << 3));
            {
                const __half2* hp = (const __half2*)&v0;
                float2 f;
                f = __half22float2(hp[0]); a0 += f.x; a1 += f.y;
                f = __half22float2(hp[1]); a2 += f.x; a3 += f.y;
                f = __half22float2(hp[2]); a4 += f.x; a5 += f.y;
                f = __half22float2(hp[3]); a6 += f.x; a7 += f.y;
            }
            {
                const __half2* hp = (const __half2*)&v1;
                float2 f;
                f = __half22float2(hp[0]); a0 += f.x; a1 += f.y;
                f = __half22float2(hp[1]); a2 += f.x; a3 += f.y;
                f = __half22float2(hp[2]); a4 += f.x; a5 += f.y;
                f = __half22float2(hp[3]); a6 += f.x; a7 += f.y;
            }
        }
        // reduce over the 16 row-slots (lane bits 2..5)
        #pragma unroll
        for (int m = 4; m <= 32; m <<= 1) {
            a0 += __shfl_xor(a0, m); a1 += __shfl_xor(a1, m);
            a2 += __shfl_xor(a2, m); a3 += __shfl_xor(a3, m);
            a4 += __shfl_xor(a4, m); a5 += __shfl_xor(a5, m);
            a6 += __shfl_xor(a6, m); a7 += __shfl_xor(a7, m);
        }
        // redistribute: dim d lives in lane (d>>3), float slot (d&7)
        int srcl = l32 >> 3;
        float t0 = __shfl(a0, srcl), t1 = __shfl(a1, srcl);
        float t2 = __shfl(a2, srcl), t3 = __shfl(a3, srcl);
        float t4 = __shfl(a4, srcl), t5 = __shfl(a5, srcl);
        float t6 = __shfl(a6, srcl), t7 = __shfl(a7, srcl);
        int c = l32 & 7;
        float H = (c == 0) ? t0 : (c == 1) ? t1 : (c == 2) ? t2 : (c == 3) ? t3
                : (c == 4) ? t4 : (c == 5) ? t5 : (c == 6) ? t6 : t7;
        H += __half2float(hin[((size_t)node << 5) + l32]);   // self term
        float deg1 = (float)(re - rs + 1);
        float v = ba + deg1 * cwl[l32];
        #pragma unroll
        for (int k = 0; k < DIM; ++k)
            v += __shfl(H, k, 32) * Wpl[k * DIM + l32];
        float acc = fmaxf(v, 0.f);
        float y = bbv;
        #pragma unroll
        for (int k = 0; k < DIM; ++k)
            y += __shfl(acc, k, 32) * Wbl[k * DIM + l32];
        y = fmaxf(y, 0.f);
        if (l < 32) {
            hout[((size_t)node << 5) + l32] = __float2half(y);
            ls += y;
            lss += y * y;
        }
    }
    if (l < 32) {
        atomicAdd(&lsum[l32], ls);
        atomicAdd(&lsumsq[l32], lss);
    }
    __syncthreads();
    if (threadIdx.x < DIM) {
        atomicAdd(&stats[threadIdx.x], lsum[threadIdx.x]);
        atomicAdd(&stats[DIM + threadIdx.x], lsumsq[threadIdx.x]);
    }
}

// ---------------- final BN + global_add_pool (run-length, batch sorted) ----------------
#define POOL_BLOCKS 512
__global__ __launch_bounds__(256) void bn_pool_kernel(const __half* __restrict__ h,
                                                      const float* __restrict__ stats,
                                                      const float* __restrict__ gamma,
                                                      const float* __restrict__ beta,
                                                      const int* __restrict__ batch,
                                                      float* __restrict__ pooled) {
    int lane = threadIdx.x & 31;
    int group = threadIdx.x >> 5;
    float mu = stats[lane] * (1.f / N_NODES);
    float var = stats[DIM + lane] * (1.f / N_NODES) - mu * mu;
    float inv = rsqrtf(var + BN_EPS);
    float a = gamma[lane] * inv;
    float c = beta[lane] - mu * a;
    const int ngroups = POOL_BLOCKS * 8;
    const int chunk = (N_NODES + ngroups - 1) / ngroups;
    int g = blockIdx.x * 8 + group;
    int start = g * chunk;
    if (start >= N_NODES) return;
    int end = start + chunk; if (end > N_NODES) end = N_NODES;
    int cur = batch[start];
    float s = 0.f;
    for (int node = start; node < end; ++node) {
        float v = __half2float(h[((size_t)node << 5) + lane]) * a + c;
        int bg = batch[node];
        if (bg != cur) {
            atomicAdd(&pooled[cur * DIM + lane], s);
            s = 0.f;
            cur = bg;
        }
        s += v;
    }
    atomicAdd(&pooled[cur * DIM + lane], s);
}

// ---------------- out = relu(pooled @ Wfc + bfc) ----------------
__global__ __launch_bounds__(256) void fc_kernel(const float* __restrict__ pooled,
                                                 const float* __restrict__ Wfc,
                                                 const float* __restrict__ bfc,
                                                 float* __restrict__ out) {
    __shared__ float Wl[DIM * OUT_DIM];
    for (int i = threadIdx.x; i < DIM * OUT_DIM; i += blockDim.x) Wl[i] = Wfc[i];
    __syncthreads();
    int idx = blockIdx.x * blockDim.x + threadIdx.x;
    int stride = gridDim.x * blockDim.x;
    for (; idx < N_GRAPHS * OUT_DIM; idx += stride) {
        int g = idx >> 7;
        int o = idx & 127;
        float acc = bfc[o];
        #pragma unroll
        for (int k = 0; k < DIM; ++k)
            acc += pooled[g * DIM + k] * Wl[k * OUT_DIM + o];
        out[idx] = fmaxf(acc, 0.f);
    }
}

extern "C" void kernel_launch(void* const* d_in, const int* in_sizes, int n_in,
                              void* d_out, int out_size, void* d_ws, size_t ws_size,
                              hipStream_t stream) {
    const float* x   = (const float*)d_in[0];
    const int* eidx  = (const int*)d_in[1];
    const int* src   = eidx;
    const int* dst   = eidx + N_EDGES;
    const int* batch = (const int*)d_in[2];
    const float* W1a = (const float*)d_in[3];
    const float* b1a = (const float*)d_in[4];
    const float* W1b = (const float*)d_in[5];
    const float* b1b = (const float*)d_in[6];
    const float* Wa  = (const float*)d_in[7];
    const float* ba  = (const float*)d_in[8];
    const float* Wb  = (const float*)d_in[9];
    const float* bb  = (const float*)d_in[10];
    const float* gamma = (const float*)d_in[11];
    const float* beta  = (const float*)d_in[12];
    const float* Wfc = (const float*)d_in[13];
    const float* bfc = (const float*)d_in[14];
    float* out = (float*)d_out;

    // workspace layout
    __half* t16 = (__half*)d_ws;                          // 3.2M halfs (6.4 MB)
    __half* h_a = t16 + (size_t)N_NODES * DIM;            // 3.2M halfs
    __half* h_b = h_a + (size_t)N_NODES * DIM;            // 3.2M halfs
    float* stats  = (float*)(h_b + (size_t)N_NODES * DIM);// 5*64
    float* pooled = stats + 5 * 64;                       // 65536
    float* Wp     = pooled + N_GRAPHS * DIM;              // 5 * 1056
    int* csr      = (int*)(Wp + 5 * 1056);                // 3.2M
    int* rowst    = csr + N_EDGES;                        // N_NODES+1
    int* bcnt     = rowst + N_NODES + 1;                  // 256
    int* bstart   = bcnt + 256;                           // NB+1
    int* bcursor  = bstart + NB + 1;                      // 256

    // CSR-build scratch aliases (dead once transform1 runs)
    int* bsrc            = (int*)t16;      // 12.8 MB spans t16+h_a
    unsigned short* blow = (unsigned short*)h_b;  // 6.4 MB = h_b

    hipMemsetAsync(bcnt, 0, 256 * sizeof(int), stream);
    hipMemsetAsync(stats, 0, 5 * 64 * sizeof(float), stream);
    hipMemsetAsync(pooled, 0, N_GRAPHS * DIM * sizeof(float), stream);

    bucket_hist_kernel<<<1024, 256, 0, stream>>>(dst, bcnt);
    bucket_scan_kernel<<<1, 256, 0, stream>>>(bcnt, bstart, bcursor, rowst);
    bucket_scatter_kernel<<<(N_EDGES + CHUNK - 1) / CHUNK, 256, 0, stream>>>(src, dst, bcursor, bsrc, blow);
    node_sort_kernel<<<NB, 256, 0, stream>>>(bstart, bsrc, blow, csr, rowst);

    transform1_kernel<<<2048, 256, 0, stream>>>(x, W1a, t16);

    prep_id_kernel<<<1, 1024, 0, stream>>>(Wp);
    agg_kernel<<<2048, 256, 0, stream>>>(t16, rowst, csr, Wp, b1a, W1b, b1b, h_a, stats + 0);

    const __half* hin = h_a;
    __half* hout = h_b;
    for (int i = 0; i < 4; ++i) {
        float* Wpi = Wp + (i + 1) * 1056;
        prep_kernel<<<1, 1024, 0, stream>>>(stats + i * 64, gamma + i * DIM, beta + i * DIM,
                                            Wa + i * DIM * DIM, Wpi);
        agg_kernel<<<2048, 256, 0, stream>>>(hin, rowst, csr, Wpi, ba + i * DIM,
                                             Wb + i * DIM * DIM, bb + i * DIM,
                                             hout, stats + (i + 1) * 64);
        __half* tmp = (__half*)hin; hin = hout; hout = tmp;
    }
    // after 4 swaps: layer-5 output is in h_a
    bn_pool_kernel<<<POOL_BLOCKS, 256, 0, stream>>>(h_a, stats + 4 * 64,
                                                    gamma + 4 * DIM, beta + 4 * DIM, batch, pooled);
    fc_kernel<<<1024, 256, 0, stream>>>(pooled, Wfc, bfc, out);
}